// Round 7
// baseline (299.531 us; speedup 1.0000x reference)
//
#include <hip/hip_runtime.h>
#include <hip/hip_bf16.h>
#include <cstdint>

// ---------------------------------------------------------------------------
// GAT forward, N=4096, F=512, D=64, H=8, O=128, fp32 in/out.
// Identity: exp(lrelu(u)) = max(exp(u), exp(0.2u)); u = s1_i+s2_j rank-1;
// softmax row-scale invariance => p'_ij = max(E2_j, g_i*F2_j), g=exp(-0.8 s1).
// Round-7: agg epilogue rewritten to LANE-CONTIGUOUS permuted Hpart layout
//   [plane=jz*NC+c][rowblk][rt][half][lane][4] (two bf16x8 stores per rt,
//   64 lanes x 16B contiguous = 1KB/inst) -- replaces the 64-line-scatter
//   stores that pinned agg at ~78us through R1-R6. fin1/fin2 read the
//   permuted layout coalesced and un-permute via padded LDS tiles; zfin
//   precomputes invZ per row.
// ---------------------------------------------------------------------------

using bf16_t = __bf16;
using bf16x4 = __attribute__((ext_vector_type(4))) __bf16;
using bf16x8 = __attribute__((ext_vector_type(8))) __bf16;
using f32x4  = __attribute__((ext_vector_type(4))) float;
using u32x4  = __attribute__((ext_vector_type(4))) uint32_t;

#define LOG2E 1.44269504f
constexpr int NN = 4096;

// ---- pack adjacency into bitmask: bit j of word [i][j/32] = (adj[i][j] > 0)
__global__ __launch_bounds__(256) void pack_bits_k(const int* __restrict__ adj,
                                                   uint32_t* __restrict__ bits, int total) {
    int stride = gridDim.x * blockDim.x;
    for (int idx = blockIdx.x * blockDim.x + threadIdx.x; idx < total; idx += stride) {
        unsigned long long m = __ballot(adj[idx] > 0);
        int l = threadIdx.x & 63;
        if (l == 0)        bits[idx >> 5] = (uint32_t)m;
        else if (l == 32)  bits[idx >> 5] = (uint32_t)(m >> 32);
    }
}

// ---- prep: x->bf16, W_heads [H][F][D] -> WT1[(h*64+d)][F], W_out -> WoutT[o][512]
__global__ __launch_bounds__(256) void prep_k(const float* __restrict__ x,
                                              const float* __restrict__ Wh,
                                              const float* __restrict__ Wo,
                                              bf16_t* __restrict__ xb,
                                              bf16_t* __restrict__ WT1,
                                              bf16_t* __restrict__ WoutT) {
    const int NX = NN * 512, NW1 = 512 * 512, NW2 = 128 * 512;
    int stride = gridDim.x * blockDim.x;
    for (int t = blockIdx.x * blockDim.x + threadIdx.x; t < NX + NW1 + NW2; t += stride) {
        if (t < NX) {
            xb[t] = (bf16_t)x[t];
        } else if (t < NX + NW1) {
            int u = t - NX; int hd = u >> 9, f = u & 511; int h = hd >> 6, d = hd & 63;
            WT1[u] = (bf16_t)Wh[(h << 15) + (f << 6) + d];
        } else {
            int u = t - NX - NW1; int o = u >> 9, cc = u & 511;
            WoutT[u] = (bf16_t)Wo[cc * 128 + o];
        }
    }
}

// ---- bf16 MFMA GEMM, 4 waves/block, wave = 16 rows x 64 cols.
// CS: epilogue writes VT (bf16 transposed) + g/E2/F2 factors (cb = head*64)
// WC: writes fp32 partial C slice (split-K via blockIdx.z)
template<int CS, int WC>
__global__ __launch_bounds__(256) void gemm_k(const bf16_t* __restrict__ A,
                                              const bf16_t* __restrict__ BT,
                                              bf16_t* __restrict__ VTo,
                                              float* __restrict__ Cp,
                                              const float* __restrict__ a1,
                                              const float* __restrict__ a2,
                                              float* __restrict__ g1,
                                              float* __restrict__ E2,
                                              float* __restrict__ F2,
                                              int K, int NC, int kslice) {
    const int wave = threadIdx.x >> 6, lane = threadIdx.x & 63;
    const int lr = lane & 15, kg = lane >> 4;
    const int rowb = (blockIdx.x * 4 + wave) * 16, cb = blockIdx.y * 64, kz = blockIdx.z;
    f32x4 acc[4];
#pragma unroll
    for (int dt = 0; dt < 4; ++dt) acc[dt] = 0.0f;
    const bf16_t* Ap = A + (size_t)(rowb + lr) * K;
    const int k0beg = kz * kslice, k0end = k0beg + kslice;
    for (int k0 = k0beg; k0 < k0end; k0 += 32) {
        bf16x8 af = *(const bf16x8*)(Ap + k0 + kg * 8);
#pragma unroll
        for (int dt = 0; dt < 4; ++dt) {
            bf16x8 bfr = *(const bf16x8*)(BT + (size_t)(cb + dt * 16 + lr) * K + k0 + kg * 8);
            acc[dt] = __builtin_amdgcn_mfma_f32_16x16x32_bf16(af, bfr, acc[dt], 0, 0, 0);
        }
    }
    if (WC) {
#pragma unroll
        for (int dt = 0; dt < 4; ++dt)
#pragma unroll
            for (int r = 0; r < 4; ++r)
                Cp[((size_t)kz * NN + rowb + kg * 4 + r) * NC + cb + dt * 16 + lr] = acc[dt][r];
    }
    if (CS) {
#pragma unroll
        for (int dt = 0; dt < 4; ++dt) {
            bf16x4 v;
#pragma unroll
            for (int r = 0; r < 4; ++r) v[r] = (bf16_t)acc[dt][r];
            *(bf16x4*)(VTo + (size_t)(cb + dt * 16 + lr) * NN + rowb + kg * 4) = v;
        }
        float a1v[4], a2v[4];
#pragma unroll
        for (int dt = 0; dt < 4; ++dt) {
            a1v[dt] = a1[cb + dt * 16 + lr];
            a2v[dt] = a2[cb + dt * 16 + lr];
        }
#pragma unroll
        for (int r = 0; r < 4; ++r) {
            float d1 = 0.f, d2 = 0.f;
#pragma unroll
            for (int dt = 0; dt < 4; ++dt) { d1 += acc[dt][r] * a1v[dt]; d2 += acc[dt][r] * a2v[dt]; }
#pragma unroll
            for (int o = 1; o < 16; o <<= 1) { d1 += __shfl_xor(d1, o); d2 += __shfl_xor(d2, o); }
            if (lr == 0) {
                size_t row = (size_t)blockIdx.y * NN + rowb + kg * 4 + r;
                g1[row] = exp2f(-0.8f * LOG2E * d1);
                E2[row] = exp2f(LOG2E * d2);
                F2[row] = exp2f(0.2f * LOG2E * d2);
            }
        }
    }
}

// ---- fused attention-aggregate, LDS-staged, lane-contiguous epilogue.
// Block = 4 waves sharing (c, jz); wave w rows = blockIdx.x*256 + w*64 .. +64.
// Hpart layout: [plane=jz*NC+c][rowblk(64)][rt(4)][half(2)][lane(64)][4]
//   half0 = {acc[rt][0][0..3], acc[rt][1][0..3]}, half1 = dt 2,3.
template<int JR, int ZC>
__global__ __launch_bounds__(256, 3) void gat_agg_k(const float* __restrict__ g1,
                                                    const float* __restrict__ E2,
                                                    const float* __restrict__ F2, int shead,
                                                    const uint32_t* __restrict__ bits,
                                                    const bf16_t* __restrict__ VT,
                                                    bf16_t* __restrict__ Hpart,
                                                    float* __restrict__ zpart) {
    constexpr int WPR = JR / 32;
    constexpr int CHUNKS = JR / 64;
    constexpr int PW = WPR + 4;
    constexpr int SEGS = WPR / 4;

    __shared__ bf16_t vtl[2][4096];
    __shared__ uint32_t bl[256][PW];
    __shared__ float el[JR], fl[JR];

    const int tid = threadIdx.x, wave = tid >> 6, lane = tid & 63;
    const int lr = lane & 15, kg = lane >> 4;
    const int c = blockIdx.y, jz = blockIdx.z, cb = c * 64;
    const int rowb0 = blockIdx.x * 256, rowb = rowb0 + wave * 64;
    const int rowblk = blockIdx.x * 4 + wave;
    const int jb0 = jz * JR;
    const float* gp  = g1 + (size_t)shead * c;
    const float* E2p = E2 + (size_t)shead * c;
    const float* F2p = F2 + (size_t)shead * c;

    // stage bits slice
#pragma unroll
    for (int r0 = 0; r0 < 256; r0 += 256 / SEGS) {
        int row = r0 + tid / SEGS, seg = tid % SEGS;
        u32x4 w = *(const u32x4*)(bits + (size_t)(rowb0 + row) * (NN / 32) + jz * WPR + seg * 4);
        *(u32x4*)&bl[row][seg * 4] = w;
    }
    // stage E2/F2 slice
    if (tid < 128) {
        if (tid < JR / 4) *(f32x4*)&el[tid * 4] = *(const f32x4*)(E2p + jb0 + tid * 4);
    } else {
        int t2 = tid - 128;
        if (t2 < JR / 4) *(f32x4*)&fl[t2 * 4] = *(const f32x4*)(F2p + jb0 + t2 * 4);
    }

    f32x4 acc[4][4];
#pragma unroll
    for (int rt = 0; rt < 4; ++rt)
#pragma unroll
        for (int dt = 0; dt < 4; ++dt) acc[rt][dt] = 0.0f;
    float zacc[4] = {0.f, 0.f, 0.f, 0.f};
    float gv[4];
#pragma unroll
    for (int rt = 0; rt < 4; ++rt) gv[rt] = gp[rowb + rt * 16 + lr];

    const int scol = tid >> 2, sseg = tid & 3;
    const bf16_t* vsrc = VT + (size_t)(cb + scol) * NN + jb0 + sseg * 16;
    const int swz_s = (scol & 7) << 4;
    const int sb0 = scol * 128 + sseg * 32;
    auto SLOAD = [&](int ch, bf16x8& a, bf16x8& b) {
        a = *(const bf16x8*)(vsrc + ch * 64);
        b = *(const bf16x8*)(vsrc + ch * 64 + 8);
    };
    auto SWRITE = [&](int buf, bf16x8 a, bf16x8 b) {
        char* base = (char*)&vtl[buf][0];
        *(bf16x8*)(base + (sb0 ^ swz_s)) = a;
        *(bf16x8*)(base + ((sb0 + 16) ^ swz_s)) = b;
    };

    bf16x8 sa, sb;
    SLOAD(0, sa, sb);
    SWRITE(0, sa, sb);
    __syncthreads();

    int cur = 0;
#pragma unroll 2
    for (int ch = 0; ch < CHUNKS; ++ch) {
        bf16x8 na, nb;
        if (ch + 1 < CHUNKS) SLOAD(ch + 1, na, nb);
#pragma unroll
        for (int js2 = 0; js2 < 2; ++js2) {
            const int js = ch * 2 + js2;
            f32x4 e2a = *(const f32x4*)&el[js * 32 + kg * 8];
            f32x4 e2b = *(const f32x4*)&el[js * 32 + kg * 8 + 4];
            f32x4 f2a = *(const f32x4*)&fl[js * 32 + kg * 8];
            f32x4 f2b = *(const f32x4*)&fl[js * 32 + kg * 8 + 4];
            bf16x8 bfr[4];
            char* vbase = (char*)&vtl[cur][0];
#pragma unroll
            for (int dt = 0; dt < 4; ++dt) {
                int col = dt * 16 + lr;
                bfr[dt] = *(const bf16x8*)(vbase +
                    ((col * 128 + js2 * 64 + kg * 16) ^ ((col & 7) << 4)));
            }
#pragma unroll
            for (int rt = 0; rt < 4; ++rt) {
                uint32_t mb = (bl[wave * 64 + rt * 16 + lr][js] >> (kg * 8)) & 0xffu;
                bf16x8 af;
                float zs = 0.f;
#pragma unroll
                for (int e = 0; e < 8; ++e) {
                    float e2 = (e < 4) ? e2a[e] : e2b[e - 4];
                    float f2 = (e < 4) ? f2a[e] : f2b[e - 4];
                    float p = fmaxf(e2, gv[rt] * f2);
                    p = (mb & (1u << e)) ? p : 0.0f;
                    zs += p;
                    af[e] = (bf16_t)p;
                }
                zacc[rt] += zs;
#pragma unroll
                for (int dt = 0; dt < 4; ++dt)
                    acc[rt][dt] = __builtin_amdgcn_mfma_f32_16x16x32_bf16(af, bfr[dt], acc[rt][dt], 0, 0, 0);
            }
        }
        if (ch + 1 < CHUNKS) SWRITE(cur ^ 1, na, nb);
        __syncthreads();
        cur ^= 1;
    }

    // ---- lane-contiguous epilogue: 2 x bf16x8 per rt, 64 lanes x 16B = 1KB/inst
    bf16_t* Hp = Hpart + (((size_t)(jz * gridDim.y + c) * 64 + rowblk) * 4096) + lane * 8;
#pragma unroll
    for (int rt = 0; rt < 4; ++rt) {
        bf16x8 h0, h1;
#pragma unroll
        for (int r = 0; r < 4; ++r) {
            h0[r]     = (bf16_t)acc[rt][0][r];
            h0[4 + r] = (bf16_t)acc[rt][1][r];
            h1[r]     = (bf16_t)acc[rt][2][r];
            h1[4 + r] = (bf16_t)acc[rt][3][r];
        }
        *(bf16x8*)(Hp + rt * 1024) = h0;
        *(bf16x8*)(Hp + rt * 1024 + 512) = h1;
    }
#pragma unroll
    for (int rt = 0; rt < 4; ++rt) {
        float z = zacc[rt];
        z += __shfl_xor(z, 16);
        z += __shfl_xor(z, 32);
        if (lane < 16 && (ZC > 1 || c == 0)) {
            int zi = jz * ZC + (ZC > 1 ? c : 0);
            zpart[(size_t)zi * NN + rowb + rt * 16 + lr] = z;
        }
    }
}

// ---- invZ precompute: invZ[g*4096+row] = 1 / sum_jz zpart[(jz*NG+g)*4096+row]
template<int NJZ, int NG>
__global__ __launch_bounds__(256) void zfin_k(const float* __restrict__ zpart,
                                              float* __restrict__ invZ) {
    int t = blockIdx.x * 256 + threadIdx.x;
    int g = t >> 12, row = t & 4095;
    float z = 0.f;
#pragma unroll
    for (int jz = 0; jz < NJZ; ++jz) z += zpart[(((size_t)(jz * NG + g)) << 12) + row];
    invZ[t] = 1.0f / z;
}

// ---- finalize layer 1: read permuted Hpart coalesced, ELU(H*invZ),
// un-permute via padded LDS tile, write hcatb row-major. Wave=(rowblk,head).
__global__ __launch_bounds__(256) void fin1_k(const bf16_t* __restrict__ Hpart,
                                              const float* __restrict__ invZ1,
                                              bf16_t* __restrict__ hcatb) {
    __shared__ bf16_t tile[4][64 * 72];
    const int tid = threadIdx.x, wave = tid >> 6, lane = tid & 63;
    const int lr = lane & 15, kg = lane >> 4;
    const int rb = blockIdx.x * 4 + wave, h = blockIdx.y;
    bf16_t* tl = tile[wave];
#pragma unroll
    for (int rt = 0; rt < 4; ++rt) {
        float hs[16];
#pragma unroll
        for (int e = 0; e < 16; ++e) hs[e] = 0.f;
#pragma unroll
        for (int jz = 0; jz < 8; ++jz) {
            const bf16_t* p = Hpart + (((size_t)(jz * 8 + h) * 64 + rb) * 4096) + rt * 1024 + lane * 8;
            bf16x8 a = *(const bf16x8*)p;
            bf16x8 b = *(const bf16x8*)(p + 512);
#pragma unroll
            for (int e = 0; e < 8; ++e) { hs[e] += (float)a[e]; hs[8 + e] += (float)b[e]; }
        }
        f32x4 iz = *(const f32x4*)(invZ1 + ((size_t)h << 12) + rb * 64 + rt * 16 + kg * 4);
#pragma unroll
        for (int dt = 0; dt < 4; ++dt)
#pragma unroll
            for (int r = 0; r < 4; ++r) {
                float v = hs[dt * 4 + r] * iz[r];
                v = v > 0.f ? v : expm1f(v);
                tl[(rt * 16 + kg * 4 + r) * 72 + dt * 16 + lr] = (bf16_t)v;
            }
    }
    __syncthreads();
#pragma unroll
    for (int it = 0; it < 8; ++it) {
        int rowL = it * 8 + (lane >> 3), seg = lane & 7;
        bf16x8 t = *(const bf16x8*)&tl[rowL * 72 + seg * 8];
        *(bf16x8*)(hcatb + ((size_t)(rb * 64 + rowL) << 9) + h * 64 + seg * 8) = t;
    }
}

// ---- combine split-K gemm2 slices: VT2 bf16 + g/E2/F2 factors. block=128thr=1 row.
__global__ __launch_bounds__(128) void comb2_k(const float* __restrict__ Cp,
                                               const float* __restrict__ a1o,
                                               const float* __restrict__ a2o,
                                               bf16_t* __restrict__ VT2,
                                               float* __restrict__ g1o,
                                               float* __restrict__ E2o,
                                               float* __restrict__ F2o) {
    int r = blockIdx.x, t = threadIdx.x;
    float w = 0.f;
#pragma unroll
    for (int z = 0; z < 4; ++z) w += Cp[((size_t)z * NN + r) * 128 + t];
    VT2[(size_t)t * NN + r] = (bf16_t)w;
    float d1 = w * a1o[t], d2 = w * a2o[t];
#pragma unroll
    for (int o = 1; o < 64; o <<= 1) { d1 += __shfl_xor(d1, o); d2 += __shfl_xor(d2, o); }
    __shared__ float red[4];
    if ((t & 63) == 0) { red[(t >> 6) * 2 + 0] = d1; red[(t >> 6) * 2 + 1] = d2; }
    __syncthreads();
    if (t == 0) {
        float s1 = red[0] + red[2], s2 = red[1] + red[3];
        g1o[r] = exp2f(-0.8f * LOG2E * s1);
        E2o[r] = exp2f(LOG2E * s2);
        F2o[r] = exp2f(0.2f * LOG2E * s2);
    }
}

// ---- finalize layer 2: same as fin1 but fp32 out, 16 jz planes, NC=2.
__global__ __launch_bounds__(256) void fin2_k(const bf16_t* __restrict__ Hpart,
                                              const float* __restrict__ invZ2,
                                              float* __restrict__ out) {
    __shared__ float tile[4][64 * 72];
    const int tid = threadIdx.x, wave = tid >> 6, lane = tid & 63;
    const int lr = lane & 15, kg = lane >> 4;
    const int rb = blockIdx.x * 4 + wave, c = blockIdx.y;
    float* tl = tile[wave];
#pragma unroll
    for (int rt = 0; rt < 4; ++rt) {
        float hs[16];
#pragma unroll
        for (int e = 0; e < 16; ++e) hs[e] = 0.f;
#pragma unroll
        for (int jz = 0; jz < 16; ++jz) {
            const bf16_t* p = Hpart + (((size_t)(jz * 2 + c) * 64 + rb) * 4096) + rt * 1024 + lane * 8;
            bf16x8 a = *(const bf16x8*)p;
            bf16x8 b = *(const bf16x8*)(p + 512);
#pragma unroll
            for (int e = 0; e < 8; ++e) { hs[e] += (float)a[e]; hs[8 + e] += (float)b[e]; }
        }
        f32x4 iz = *(const f32x4*)(invZ2 + rb * 64 + rt * 16 + kg * 4);
#pragma unroll
        for (int dt = 0; dt < 4; ++dt)
#pragma unroll
            for (int r = 0; r < 4; ++r)
                tl[(rt * 16 + kg * 4 + r) * 72 + dt * 16 + lr] = hs[dt * 4 + r] * iz[r];
    }
    __syncthreads();
#pragma unroll
    for (int it = 0; it < 16; ++it) {
        int rowL = it * 4 + (lane >> 4), seg = lane & 15;
        f32x4 t = *(const f32x4*)&tl[rowL * 72 + seg * 4];
        *(f32x4*)(out + ((size_t)(rb * 64 + rowL) << 7) + c * 64 + seg * 4) = t;
    }
}

extern "C" void kernel_launch(void* const* d_in, const int* in_sizes, int n_in,
                              void* d_out, int out_size, void* d_ws, size_t ws_size,
                              hipStream_t stream) {
    const int N = 4096;
    const float* x       = (const float*)d_in[0];
    const int*   adj     = (const int*)d_in[1];
    const float* W_heads = (const float*)d_in[2];
    const float* a1h     = (const float*)d_in[3];
    const float* a2h     = (const float*)d_in[4];
    const float* W_out   = (const float*)d_in[5];
    const float* a1o     = (const float*)d_in[6];
    const float* a2o     = (const float*)d_in[7];
    (void)in_sizes; (void)n_in; (void)out_size; (void)ws_size;

    size_t off = 0;
    auto alloc = [&](size_t bytes) { size_t o = off; off = (off + bytes + 255) & ~(size_t)255; return o; };
    char* ws = (char*)d_ws;
    uint32_t* bits  = (uint32_t*)(ws + alloc((size_t)N * N / 8));        // 2 MB
    bf16_t* VT1     = (bf16_t*)(ws + alloc((size_t)512 * N * 2));        // 4 MB
    bf16_t* hcatb   = (bf16_t*)(ws + alloc((size_t)N * 512 * 2));        // 4 MB
    bf16_t* WoutT   = (bf16_t*)(ws + alloc((size_t)128 * 512 * 2));      // 128 KB
    float*  g1h     = (float*)(ws + alloc((size_t)8 * N * 4));
    float*  E2h     = (float*)(ws + alloc((size_t)8 * N * 4));
    float*  F2h     = (float*)(ws + alloc((size_t)8 * N * 4));
    float*  g1o     = (float*)(ws + alloc((size_t)N * 4));
    float*  E2o     = (float*)(ws + alloc((size_t)N * 4));
    float*  F2o     = (float*)(ws + alloc((size_t)N * 4));
    bf16_t* VT2     = (bf16_t*)(ws + alloc((size_t)128 * N * 2));        // 1 MB
    float*  zpart   = (float*)(ws + alloc((size_t)64 * N * 4));          // 1 MB
    float*  invZ1   = (float*)(ws + alloc((size_t)8 * N * 4));           // 128 KB
    float*  invZ2   = (float*)(ws + alloc((size_t)N * 4));               // 16 KB
    bf16_t* Hpart   = (bf16_t*)(ws + alloc((size_t)32 * 1024 * 1024));   // 32 MB
    // aliases into the Hpart region (temporally disjoint):
    bf16_t* xb    = (bf16_t*)Hpart;                       // dead after gemm1
    bf16_t* WT1   = (bf16_t*)((char*)Hpart + (4 << 20));  // dead after gemm1
    float*  Cpart = (float*)Hpart;                        // gemm2..comb2 only (fin1 done)

    // 1. adjacency bitmask
    hipLaunchKernelGGL(pack_bits_k, dim3(2048), dim3(256), 0, stream, adj, bits, N * N);
    // 2. prep conversions/transposes
    hipLaunchKernelGGL(prep_k, dim3(1024), dim3(256), 0, stream, x, W_heads, W_out, xb, WT1, WoutT);
    // 3. gemm1: VT1 + g/E2/F2 per head  (4-wave blocks)
    hipLaunchKernelGGL((gemm_k<1, 0>), dim3(64, 8, 1), dim3(256), 0, stream,
                       xb, WT1, VT1, (float*)nullptr, a1h, a2h, g1h, E2h, F2h, 512, 512, 512);
    // 4. layer-1 aggregate: blocks (rowgrp=16, head=8, jz=8), LDS-staged
    hipLaunchKernelGGL((gat_agg_k<512, 8>), dim3(16, 8, 8), dim3(256), 0, stream,
                       g1h, E2h, F2h, N, bits, VT1, Hpart, zpart);
    // 5. invZ layer 1
    hipLaunchKernelGGL((zfin_k<8, 8>), dim3(128), dim3(256), 0, stream, zpart, invZ1);
    // 6. finalize 1 -> hcatb
    hipLaunchKernelGGL(fin1_k, dim3(16, 8), dim3(256), 0, stream, Hpart, invZ1, hcatb);
    // 7. gemm2 split-K=4 -> Cpart  (4-wave blocks)
    hipLaunchKernelGGL((gemm_k<0, 1>), dim3(64, 2, 4), dim3(256), 0, stream,
                       hcatb, WoutT, (bf16_t*)nullptr, Cpart,
                       (const float*)nullptr, (const float*)nullptr,
                       (float*)nullptr, (float*)nullptr, (float*)nullptr, 512, 128, 128);
    // 8. combine -> VT2, g1o/E2o/F2o
    hipLaunchKernelGGL(comb2_k, dim3(4096), dim3(128), 0, stream, Cpart, a1o, a2o, VT2, g1o, E2o, F2o);
    // 9. layer-2 aggregate: blocks (rowgrp=16, colgrps=2, jz=16), LDS-staged
    hipLaunchKernelGGL((gat_agg_k<256, 1>), dim3(16, 2, 16), dim3(256), 0, stream,
                       g1o, E2o, F2o, 0, bits, VT2, Hpart, zpart);
    // 10. invZ layer 2
    hipLaunchKernelGGL((zfin_k<16, 1>), dim3(16), dim3(256), 0, stream, zpart, invZ2);
    // 11. finalize 2 -> out
    hipLaunchKernelGGL(fin2_k, dim3(16, 2), dim3(256), 0, stream, Hpart, invZ2, (float*)d_out);
}

// Round 8
// 174.348 us; speedup vs baseline: 1.7180x; 1.7180x over previous
//
#include <hip/hip_runtime.h>
#include <hip/hip_bf16.h>
#include <cstdint>

// ---------------------------------------------------------------------------
// GAT forward, N=4096, F=512, D=64, H=8, O=128, fp32 in/out.
// Identity: exp(lrelu(u)) = max(exp(u), exp(0.2u)); u = s1_i+s2_j rank-1;
// softmax row-scale invariance => p'_ij = max(E2_j, g_i*F2_j), g=exp(-0.8 s1).
// Round-8 = Round-4 structure (best measured: agg 77.5us, FETCH 18.6MB,
// WRITE 33.8MB) + two surgical changes:
//   (a) Z row-sums via MFMA ones-column (matrix pipe is 91% idle) instead of
//       VALU adds + epilogue shuffles;
//   (b) XCD-colocating grid: blockIdx.x = (head/colgrp, jzgrp) composite,
//       blockIdx.y = rowtile -> linear_id % 8 is invariant in rowtile, so all
//       blocks sharing a VT slice land on the same XCD L2 (perf heuristic
//       only; correctness does not depend on the mapping).
// ---------------------------------------------------------------------------

using bf16_t = __bf16;
using bf16x4 = __attribute__((ext_vector_type(4))) __bf16;
using bf16x8 = __attribute__((ext_vector_type(8))) __bf16;
using f32x4  = __attribute__((ext_vector_type(4))) float;

#define LOG2E 1.44269504f
constexpr int NN = 4096;

// ---- pack adjacency into bitmask: bit j of word [i][j/32] = (adj[i][j] > 0)
__global__ __launch_bounds__(256) void pack_bits_k(const int* __restrict__ adj,
                                                   uint32_t* __restrict__ bits, int total) {
    int stride = gridDim.x * blockDim.x;
    for (int idx = blockIdx.x * blockDim.x + threadIdx.x; idx < total; idx += stride) {
        unsigned long long m = __ballot(adj[idx] > 0);
        int l = threadIdx.x & 63;
        if (l == 0)        bits[idx >> 5] = (uint32_t)m;
        else if (l == 32)  bits[idx >> 5] = (uint32_t)(m >> 32);
    }
}

// ---- prep: x->bf16, W_heads [H][F][D] -> WT1[(h*64+d)][F], W_out -> WoutT[o][512]
__global__ __launch_bounds__(256) void prep_k(const float* __restrict__ x,
                                              const float* __restrict__ Wh,
                                              const float* __restrict__ Wo,
                                              bf16_t* __restrict__ xb,
                                              bf16_t* __restrict__ WT1,
                                              bf16_t* __restrict__ WoutT) {
    const int NX = NN * 512, NW1 = 512 * 512, NW2 = 128 * 512;
    int stride = gridDim.x * blockDim.x;
    for (int t = blockIdx.x * blockDim.x + threadIdx.x; t < NX + NW1 + NW2; t += stride) {
        if (t < NX) {
            xb[t] = (bf16_t)x[t];
        } else if (t < NX + NW1) {
            int u = t - NX; int hd = u >> 9, f = u & 511; int h = hd >> 6, d = hd & 63;
            WT1[u] = (bf16_t)Wh[(h << 15) + (f << 6) + d];
        } else {
            int u = t - NX - NW1; int o = u >> 9, cc = u & 511;
            WoutT[u] = (bf16_t)Wo[cc * 128 + o];
        }
    }
}

// ---- bf16 MFMA GEMM, 4 waves/block, wave = 16 rows x 64 cols.
// CS: epilogue writes VT (bf16 transposed) + g/E2/F2 factors (cb = head*64)
// WC: writes fp32 partial C slice (split-K via blockIdx.z)
template<int CS, int WC>
__global__ __launch_bounds__(256) void gemm_k(const bf16_t* __restrict__ A,
                                              const bf16_t* __restrict__ BT,
                                              bf16_t* __restrict__ VTo,
                                              float* __restrict__ Cp,
                                              const float* __restrict__ a1,
                                              const float* __restrict__ a2,
                                              float* __restrict__ g1,
                                              float* __restrict__ E2,
                                              float* __restrict__ F2,
                                              int K, int NC, int kslice) {
    const int wave = threadIdx.x >> 6, lane = threadIdx.x & 63;
    const int lr = lane & 15, kg = lane >> 4;
    const int rowb = (blockIdx.x * 4 + wave) * 16, cb = blockIdx.y * 64, kz = blockIdx.z;
    f32x4 acc[4];
#pragma unroll
    for (int dt = 0; dt < 4; ++dt) acc[dt] = 0.0f;
    const bf16_t* Ap = A + (size_t)(rowb + lr) * K;
    const int k0beg = kz * kslice, k0end = k0beg + kslice;
    for (int k0 = k0beg; k0 < k0end; k0 += 32) {
        bf16x8 af = *(const bf16x8*)(Ap + k0 + kg * 8);
#pragma unroll
        for (int dt = 0; dt < 4; ++dt) {
            bf16x8 bfr = *(const bf16x8*)(BT + (size_t)(cb + dt * 16 + lr) * K + k0 + kg * 8);
            acc[dt] = __builtin_amdgcn_mfma_f32_16x16x32_bf16(af, bfr, acc[dt], 0, 0, 0);
        }
    }
    if (WC) {
#pragma unroll
        for (int dt = 0; dt < 4; ++dt)
#pragma unroll
            for (int r = 0; r < 4; ++r)
                Cp[((size_t)kz * NN + rowb + kg * 4 + r) * NC + cb + dt * 16 + lr] = acc[dt][r];
    }
    if (CS) {
#pragma unroll
        for (int dt = 0; dt < 4; ++dt) {
            bf16x4 v;
#pragma unroll
            for (int r = 0; r < 4; ++r) v[r] = (bf16_t)acc[dt][r];
            *(bf16x4*)(VTo + (size_t)(cb + dt * 16 + lr) * NN + rowb + kg * 4) = v;
        }
        float a1v[4], a2v[4];
#pragma unroll
        for (int dt = 0; dt < 4; ++dt) {
            a1v[dt] = a1[cb + dt * 16 + lr];
            a2v[dt] = a2[cb + dt * 16 + lr];
        }
#pragma unroll
        for (int r = 0; r < 4; ++r) {
            float d1 = 0.f, d2 = 0.f;
#pragma unroll
            for (int dt = 0; dt < 4; ++dt) { d1 += acc[dt][r] * a1v[dt]; d2 += acc[dt][r] * a2v[dt]; }
#pragma unroll
            for (int o = 1; o < 16; o <<= 1) { d1 += __shfl_xor(d1, o); d2 += __shfl_xor(d2, o); }
            if (lr == 0) {
                size_t row = (size_t)blockIdx.y * NN + rowb + kg * 4 + r;
                g1[row] = exp2f(-0.8f * LOG2E * d1);
                E2[row] = exp2f(LOG2E * d2);
                F2[row] = exp2f(0.2f * LOG2E * d2);
            }
        }
    }
}

// ---- fused attention-aggregate (R4 structure + Z-MFMA + XCD grid).
// grid = (CG*JZG, 64); x -> (c = x/JZG, jzgrp = x%JZG); y = rowtile.
// 4 waves/block; wave w owns jz = jzgrp*4 + w; wave = 64 rows x 64 cols.
// p'_ij = adj ? max(E2_j, g_i*F2_j) : 0. Register double-buffer (A/B sets).
// Z row-sums via extra MFMA against a ones-column B-fragment.
template<int JZG>
__global__ __launch_bounds__(256) void gat_agg_k(const float* __restrict__ g1,
                                                 const float* __restrict__ E2,
                                                 const float* __restrict__ F2, int shead,
                                                 const uint32_t* __restrict__ bits,
                                                 const bf16_t* __restrict__ VT,
                                                 bf16_t* __restrict__ Hpart,
                                                 float* __restrict__ zpart,
                                                 int CT, int JR, int ZC) {
    const int wave = threadIdx.x >> 6, lane = threadIdx.x & 63;
    const int lr = lane & 15, kg = lane >> 4;
    const int c = blockIdx.x / JZG, jzg = blockIdx.x % JZG;
    const int rowb = blockIdx.y * 64;
    const int jz = jzg * 4 + wave;
    const int cb = c * 64;
    const float* gp  = g1 + (size_t)shead * c;
    const float* E2p = E2 + (size_t)shead * c;
    const float* F2p = F2 + (size_t)shead * c;
    const int steps = JR >> 5, jb0 = jz * JR;

    f32x4 acc[4][4], accz[4];
#pragma unroll
    for (int rt = 0; rt < 4; ++rt) {
        accz[rt] = 0.0f;
#pragma unroll
        for (int dt = 0; dt < 4; ++dt) acc[rt][dt] = 0.0f;
    }
    float gv[4];
    const uint32_t* brow[4];
#pragma unroll
    for (int rt = 0; rt < 4; ++rt) {
        int row = rowb + rt * 16 + lr;
        gv[rt] = gp[row];
        brow[rt] = bits + (size_t)row * (NN / 32);
    }
    bf16x8 ones;
#pragma unroll
    for (int e = 0; e < 8; ++e) ones[e] = (bf16_t)(lr == 0 ? 1.0f : 0.0f);

    auto LOAD = [&](int jb, bf16x8* bfr, f32x4& e2a, f32x4& e2b, f32x4& f2a, f32x4& f2b,
                    uint32_t* bw) {
        const int jk = jb + kg * 8;
        e2a = *(const f32x4*)(E2p + jk);
        e2b = *(const f32x4*)(E2p + jk + 4);
        f2a = *(const f32x4*)(F2p + jk);
        f2b = *(const f32x4*)(F2p + jk + 4);
#pragma unroll
        for (int dt = 0; dt < 4; ++dt)
            bfr[dt] = *(const bf16x8*)(VT + (size_t)(cb + dt * 16 + lr) * NN + jk);
#pragma unroll
        for (int rt = 0; rt < 4; ++rt)
            bw[rt] = brow[rt][jb >> 5];
    };
    auto COMP = [&](const bf16x8* bfr, f32x4 e2a, f32x4 e2b, f32x4 f2a, f32x4 f2b,
                    const uint32_t* bw) {
#pragma unroll
        for (int rt = 0; rt < 4; ++rt) {
            uint32_t mb = (bw[rt] >> (kg * 8)) & 0xffu;
            bf16x8 af;
#pragma unroll
            for (int e = 0; e < 8; ++e) {
                float e2 = (e < 4) ? e2a[e] : e2b[e - 4];
                float f2 = (e < 4) ? f2a[e] : f2b[e - 4];
                float p = fmaxf(e2, gv[rt] * f2);
                p = (mb & (1u << e)) ? p : 0.0f;
                af[e] = (bf16_t)p;
            }
#pragma unroll
            for (int dt = 0; dt < 4; ++dt)
                acc[rt][dt] = __builtin_amdgcn_mfma_f32_16x16x32_bf16(af, bfr[dt], acc[rt][dt], 0, 0, 0);
            accz[rt] = __builtin_amdgcn_mfma_f32_16x16x32_bf16(af, ones, accz[rt], 0, 0, 0);
        }
    };

    bf16x8 bA[4], bB[4];
    f32x4 eaA, ebA, faA, fbA, eaB, ebB, faB, fbB;
    uint32_t wA[4], wB[4];
    LOAD(jb0, bA, eaA, ebA, faA, fbA, wA);
    for (int js = 0; js < steps - 2; js += 2) {
        LOAD(jb0 + (js + 1) * 32, bB, eaB, ebB, faB, fbB, wB);
        COMP(bA, eaA, ebA, faA, fbA, wA);
        LOAD(jb0 + (js + 2) * 32, bA, eaA, ebA, faA, fbA, wA);
        COMP(bB, eaB, ebB, faB, fbB, wB);
    }
    LOAD(jb0 + (steps - 1) * 32, bB, eaB, ebB, faB, fbB, wB);
    COMP(bA, eaA, ebA, faA, fbA, wA);
    COMP(bB, eaB, ebB, faB, fbB, wB);

    bf16_t* Hp = Hpart + (size_t)jz * NN * CT;
#pragma unroll
    for (int rt = 0; rt < 4; ++rt) {
#pragma unroll
        for (int dt = 0; dt < 4; ++dt)
#pragma unroll
            for (int r = 0; r < 4; ++r)
                Hp[(size_t)(rowb + rt * 16 + kg * 4 + r) * CT + cb + dt * 16 + lr] = (bf16_t)acc[rt][dt][r];
    }
    if (lr == 0 && (ZC > 1 || c == 0)) {
        int zi = jz * ZC + (ZC > 1 ? c : 0);
#pragma unroll
        for (int rt = 0; rt < 4; ++rt)
#pragma unroll
            for (int r = 0; r < 4; ++r)
                zpart[(size_t)zi * NN + rowb + rt * 16 + kg * 4 + r] = accz[rt][r];
    }
}

// ---- finalize layer 1: hcatb = bf16(ELU(sum H / sum Z)), 8 cols/thread
__global__ __launch_bounds__(256) void fin1_k(const bf16_t* __restrict__ Hpart,
                                              const float* __restrict__ zpart,
                                              bf16_t* __restrict__ hcatb) {
    int idx = blockIdx.x * 256 + threadIdx.x;   // < N*64
    int i = idx >> 6, col0 = (idx & 63) << 3, h = col0 >> 6;
    float Z = 0.f;
#pragma unroll
    for (int jz = 0; jz < 8; ++jz) Z += zpart[(size_t)(jz * 8 + h) * NN + i];
    float hs[8];
#pragma unroll
    for (int e = 0; e < 8; ++e) hs[e] = 0.f;
#pragma unroll
    for (int jz = 0; jz < 8; ++jz) {
        bf16x8 v = *(const bf16x8*)(Hpart + ((size_t)jz * NN + i) * 512 + col0);
#pragma unroll
        for (int e = 0; e < 8; ++e) hs[e] += (float)v[e];
    }
    float invZ = 1.0f / Z;
    bf16x8 o;
#pragma unroll
    for (int e = 0; e < 8; ++e) {
        float v = hs[e] * invZ;
        o[e] = (bf16_t)(v > 0.f ? v : expm1f(v));
    }
    *(bf16x8*)(hcatb + (size_t)i * 512 + col0) = o;
}

// ---- combine split-K gemm2 slices: VT2 bf16 + g/E2/F2 factors. block=128thr=1 row.
__global__ __launch_bounds__(128) void comb2_k(const float* __restrict__ Cp,
                                               const float* __restrict__ a1o,
                                               const float* __restrict__ a2o,
                                               bf16_t* __restrict__ VT2,
                                               float* __restrict__ g1o,
                                               float* __restrict__ E2o,
                                               float* __restrict__ F2o) {
    int r = blockIdx.x, t = threadIdx.x;
    float w = 0.f;
#pragma unroll
    for (int z = 0; z < 4; ++z) w += Cp[((size_t)z * NN + r) * 128 + t];
    VT2[(size_t)t * NN + r] = (bf16_t)w;
    float d1 = w * a1o[t], d2 = w * a2o[t];
#pragma unroll
    for (int o = 1; o < 64; o <<= 1) { d1 += __shfl_xor(d1, o); d2 += __shfl_xor(d2, o); }
    __shared__ float red[4];
    if ((t & 63) == 0) { red[(t >> 6) * 2 + 0] = d1; red[(t >> 6) * 2 + 1] = d2; }
    __syncthreads();
    if (t == 0) {
        float s1 = red[0] + red[2], s2 = red[1] + red[3];
        g1o[r] = exp2f(-0.8f * LOG2E * s1);
        E2o[r] = exp2f(LOG2E * s2);
        F2o[r] = exp2f(0.2f * LOG2E * s2);
    }
}

// ---- finalize layer 2: out fp32 = sum H / sum Z, 8 cols/thread
__global__ __launch_bounds__(256) void fin2_k(const bf16_t* __restrict__ Hpart,
                                              const float* __restrict__ zpart,
                                              float* __restrict__ out) {
    int idx = blockIdx.x * 256 + threadIdx.x;   // < N*16
    int i = idx >> 4, col0 = (idx & 15) << 3;
    float Z = 0.f;
#pragma unroll
    for (int jz = 0; jz < 16; ++jz) Z += zpart[(size_t)jz * NN + i];
    float hs[8];
#pragma unroll
    for (int e = 0; e < 8; ++e) hs[e] = 0.f;
#pragma unroll
    for (int jz = 0; jz < 16; ++jz) {
        bf16x8 v = *(const bf16x8*)(Hpart + ((size_t)jz * NN + i) * 128 + col0);
#pragma unroll
        for (int e = 0; e < 8; ++e) hs[e] += (float)v[e];
    }
    float invZ = 1.0f / Z;
    f32x4 o0, o1;
#pragma unroll
    for (int e = 0; e < 4; ++e) { o0[e] = hs[e] * invZ; o1[e] = hs[e + 4] * invZ; }
    *(f32x4*)(out + (size_t)i * 128 + col0) = o0;
    *(f32x4*)(out + (size_t)i * 128 + col0 + 4) = o1;
}

extern "C" void kernel_launch(void* const* d_in, const int* in_sizes, int n_in,
                              void* d_out, int out_size, void* d_ws, size_t ws_size,
                              hipStream_t stream) {
    const int N = 4096;
    const float* x       = (const float*)d_in[0];
    const int*   adj     = (const int*)d_in[1];
    const float* W_heads = (const float*)d_in[2];
    const float* a1h     = (const float*)d_in[3];
    const float* a2h     = (const float*)d_in[4];
    const float* W_out   = (const float*)d_in[5];
    const float* a1o     = (const float*)d_in[6];
    const float* a2o     = (const float*)d_in[7];
    (void)in_sizes; (void)n_in; (void)out_size; (void)ws_size;

    size_t off = 0;
    auto alloc = [&](size_t bytes) { size_t o = off; off = (off + bytes + 255) & ~(size_t)255; return o; };
    char* ws = (char*)d_ws;
    uint32_t* bits  = (uint32_t*)(ws + alloc((size_t)N * N / 8));        // 2 MB
    bf16_t* VT1     = (bf16_t*)(ws + alloc((size_t)512 * N * 2));        // 4 MB
    bf16_t* hcatb   = (bf16_t*)(ws + alloc((size_t)N * 512 * 2));        // 4 MB
    bf16_t* WoutT   = (bf16_t*)(ws + alloc((size_t)128 * 512 * 2));      // 128 KB
    float*  g1h     = (float*)(ws + alloc((size_t)8 * N * 4));
    float*  E2h     = (float*)(ws + alloc((size_t)8 * N * 4));
    float*  F2h     = (float*)(ws + alloc((size_t)8 * N * 4));
    float*  g1o     = (float*)(ws + alloc((size_t)N * 4));
    float*  E2o     = (float*)(ws + alloc((size_t)N * 4));
    float*  F2o     = (float*)(ws + alloc((size_t)N * 4));
    bf16_t* VT2     = (bf16_t*)(ws + alloc((size_t)128 * N * 2));        // 1 MB
    float*  zpart   = (float*)(ws + alloc((size_t)64 * N * 4));          // 1 MB
    bf16_t* Hpart   = (bf16_t*)(ws + alloc((size_t)32 * 1024 * 1024));   // 32 MB
    // aliases into the Hpart region (temporally disjoint):
    bf16_t* xb    = (bf16_t*)Hpart;                       // dead after gemm1
    bf16_t* WT1   = (bf16_t*)((char*)Hpart + (4 << 20));  // dead after gemm1
    float*  Cpart = (float*)Hpart;                        // gemm2..comb2 only

    // 1. adjacency bitmask
    hipLaunchKernelGGL(pack_bits_k, dim3(2048), dim3(256), 0, stream, adj, bits, N * N);
    // 2. prep conversions/transposes
    hipLaunchKernelGGL(prep_k, dim3(1024), dim3(256), 0, stream, x, W_heads, W_out, xb, WT1, WoutT);
    // 3. gemm1: VT1 + g/E2/F2 per head  (4-wave blocks)
    hipLaunchKernelGGL((gemm_k<1, 0>), dim3(64, 8, 1), dim3(256), 0, stream,
                       xb, WT1, VT1, (float*)nullptr, a1h, a2h, g1h, E2h, F2h, 512, 512, 512);
    // 4. layer-1 aggregate: grid x=(head,jzgrp)=16, y=rowtile=64; jz = jzgrp*4+wave
    hipLaunchKernelGGL((gat_agg_k<2>), dim3(16, 64, 1), dim3(256), 0, stream,
                       g1h, E2h, F2h, N, bits, VT1, Hpart, zpart, 512, 512, 8);
    // 5. finalize 1 -> hcatb
    hipLaunchKernelGGL(fin1_k, dim3(1024), dim3(256), 0, stream, Hpart, zpart, hcatb);
    // 6. gemm2 split-K=4 -> Cpart  (4-wave blocks)
    hipLaunchKernelGGL((gemm_k<0, 1>), dim3(64, 2, 4), dim3(256), 0, stream,
                       hcatb, WoutT, (bf16_t*)nullptr, Cpart,
                       (const float*)nullptr, (const float*)nullptr,
                       (float*)nullptr, (float*)nullptr, (float*)nullptr, 512, 128, 128);
    // 7. combine -> VT2, g1o/E2o/F2o
    hipLaunchKernelGGL(comb2_k, dim3(4096), dim3(128), 0, stream, Cpart, a1o, a2o, VT2, g1o, E2o, F2o);
    // 8. layer-2 aggregate: grid x=(c,jzgrp)=8, y=rowtile=64; jz = jzgrp*4+wave
    hipLaunchKernelGGL((gat_agg_k<4>), dim3(8, 64, 1), dim3(256), 0, stream,
                       g1o, E2o, F2o, 0, bits, VT2, Hpart, zpart, 128, 256, 1);
    // 9. finalize 2 -> out
    hipLaunchKernelGGL(fin2_k, dim3(256), dim3(256), 0, stream, Hpart, zpart, (float*)d_out);
}

// Round 9
// 140.963 us; speedup vs baseline: 2.1249x; 1.2368x over previous
//
#include <hip/hip_runtime.h>
#include <hip/hip_bf16.h>
#include <cstdint>

// ---------------------------------------------------------------------------
// GAT forward, N=4096, F=512, D=64, H=8, O=128, fp32 in/out.
// Identity: exp(lrelu(u)) = max(exp(u), exp(0.2u)); u = s1_i+s2_j rank-1;
// softmax row-scale invariance => p'_ij = max(E2_j, g_i*F2_j), g=exp(-0.8 s1).
// Round-9: attack the cache-line REQUEST count (per-step: ~190 sparse line
// requests -> ~4500cy/step queueing, the invariant wall of R1-R8):
//   (a) V stored j-tiled:  VTt[j/32][col][j%32]  -> each MFMA B-frag load is
//       16 lanes x 64B-apart = dense 1KB, 8 lines/inst (was 16 sparse).
//   (b) bitmask transposed: bitsT[j/32][i] -> per-rt word load = 16 contiguous
//       words = 1 line/inst (was 16 lines).
// Keeps R8's Z-via-MFMA + XCD-colocating grid (FETCH 7.3MB confirmed).
// ---------------------------------------------------------------------------

using bf16_t = __bf16;
using bf16x4 = __attribute__((ext_vector_type(4))) __bf16;
using bf16x8 = __attribute__((ext_vector_type(8))) __bf16;
using f32x4  = __attribute__((ext_vector_type(4))) float;

#define LOG2E 1.44269504f
constexpr int NN = 4096;

// ---- pack adjacency into TRANSPOSED bitmask: bitsT[(j>>5)*N + i], bit j&31
__global__ __launch_bounds__(256) void pack_bits_k(const int* __restrict__ adj,
                                                   uint32_t* __restrict__ bitsT, int total) {
    int stride = gridDim.x * blockDim.x;
    for (int idx = blockIdx.x * blockDim.x + threadIdx.x; idx < total; idx += stride) {
        unsigned long long m = __ballot(adj[idx] > 0);
        int l = threadIdx.x & 63;
        int i = idx >> 12, j = idx & 4095;
        if (l == 0)        bitsT[(size_t)(j >> 5) * NN + i] = (uint32_t)m;
        else if (l == 32)  bitsT[(size_t)(j >> 5) * NN + i] = (uint32_t)(m >> 32);
    }
}

// ---- prep: x->bf16, W_heads [H][F][D] -> WT1[(h*64+d)][F], W_out -> WoutT[o][512]
__global__ __launch_bounds__(256) void prep_k(const float* __restrict__ x,
                                              const float* __restrict__ Wh,
                                              const float* __restrict__ Wo,
                                              bf16_t* __restrict__ xb,
                                              bf16_t* __restrict__ WT1,
                                              bf16_t* __restrict__ WoutT) {
    const int NX = NN * 512, NW1 = 512 * 512, NW2 = 128 * 512;
    int stride = gridDim.x * blockDim.x;
    for (int t = blockIdx.x * blockDim.x + threadIdx.x; t < NX + NW1 + NW2; t += stride) {
        if (t < NX) {
            xb[t] = (bf16_t)x[t];
        } else if (t < NX + NW1) {
            int u = t - NX; int hd = u >> 9, f = u & 511; int h = hd >> 6, d = hd & 63;
            WT1[u] = (bf16_t)Wh[(h << 15) + (f << 6) + d];
        } else {
            int u = t - NX - NW1; int o = u >> 9, cc = u & 511;
            WoutT[u] = (bf16_t)Wo[cc * 128 + o];
        }
    }
}

// ---- bf16 MFMA GEMM, 4 waves/block, wave = 16 rows x 64 cols.
// CS: epilogue writes VTt (j-tiled: [i/32][col][i&31]) + g/E2/F2 (cb=head*64)
// WC: writes fp32 partial C slice (split-K via blockIdx.z)
template<int CS, int WC>
__global__ __launch_bounds__(256) void gemm_k(const bf16_t* __restrict__ A,
                                              const bf16_t* __restrict__ BT,
                                              bf16_t* __restrict__ VTt,
                                              float* __restrict__ Cp,
                                              const float* __restrict__ a1,
                                              const float* __restrict__ a2,
                                              float* __restrict__ g1,
                                              float* __restrict__ E2,
                                              float* __restrict__ F2,
                                              int K, int NC, int kslice, int NCOLS) {
    const int wave = threadIdx.x >> 6, lane = threadIdx.x & 63;
    const int lr = lane & 15, kg = lane >> 4;
    const int rowb = (blockIdx.x * 4 + wave) * 16, cb = blockIdx.y * 64, kz = blockIdx.z;
    f32x4 acc[4];
#pragma unroll
    for (int dt = 0; dt < 4; ++dt) acc[dt] = 0.0f;
    const bf16_t* Ap = A + (size_t)(rowb + lr) * K;
    const int k0beg = kz * kslice, k0end = k0beg + kslice;
    for (int k0 = k0beg; k0 < k0end; k0 += 32) {
        bf16x8 af = *(const bf16x8*)(Ap + k0 + kg * 8);
#pragma unroll
        for (int dt = 0; dt < 4; ++dt) {
            bf16x8 bfr = *(const bf16x8*)(BT + (size_t)(cb + dt * 16 + lr) * K + k0 + kg * 8);
            acc[dt] = __builtin_amdgcn_mfma_f32_16x16x32_bf16(af, bfr, acc[dt], 0, 0, 0);
        }
    }
    if (WC) {
#pragma unroll
        for (int dt = 0; dt < 4; ++dt)
#pragma unroll
            for (int r = 0; r < 4; ++r)
                Cp[((size_t)kz * NN + rowb + kg * 4 + r) * NC + cb + dt * 16 + lr] = acc[dt][r];
    }
    if (CS) {
        // i = rowb + kg*4 + r  (the agg j index); tiled addr:
        // (i>>5)*NCOLS*32 + col*32 + (i&31), r contiguous in last dim.
        const int i0 = rowb + kg * 4;
        const size_t tbase = (size_t)(i0 >> 5) * NCOLS * 32 + (i0 & 31);
#pragma unroll
        for (int dt = 0; dt < 4; ++dt) {
            bf16x4 v;
#pragma unroll
            for (int r = 0; r < 4; ++r) v[r] = (bf16_t)acc[dt][r];
            *(bf16x4*)(VTt + tbase + (size_t)(cb + dt * 16 + lr) * 32) = v;
        }
        float a1v[4], a2v[4];
#pragma unroll
        for (int dt = 0; dt < 4; ++dt) {
            a1v[dt] = a1[cb + dt * 16 + lr];
            a2v[dt] = a2[cb + dt * 16 + lr];
        }
#pragma unroll
        for (int r = 0; r < 4; ++r) {
            float d1 = 0.f, d2 = 0.f;
#pragma unroll
            for (int dt = 0; dt < 4; ++dt) { d1 += acc[dt][r] * a1v[dt]; d2 += acc[dt][r] * a2v[dt]; }
#pragma unroll
            for (int o = 1; o < 16; o <<= 1) { d1 += __shfl_xor(d1, o); d2 += __shfl_xor(d2, o); }
            if (lr == 0) {
                size_t row = (size_t)blockIdx.y * NN + rowb + kg * 4 + r;
                g1[row] = exp2f(-0.8f * LOG2E * d1);
                E2[row] = exp2f(LOG2E * d2);
                F2[row] = exp2f(0.2f * LOG2E * d2);
            }
        }
    }
}

// ---- fused attention-aggregate (R8 + tiled-VT + transposed-bits loads).
// grid = (CG*JZG, 64); x -> (c = x/JZG, jzgrp = x%JZG); y = rowtile.
// 4 waves/block; wave w owns jz = jzgrp*4 + w; wave = 64 rows x 64 cols.
// p'_ij = adj ? max(E2_j, g_i*F2_j) : 0. Register double-buffer (A/B sets).
// Z row-sums via extra MFMA against a ones-column B-fragment.
template<int JZG>
__global__ __launch_bounds__(256) void gat_agg_k(const float* __restrict__ g1,
                                                 const float* __restrict__ E2,
                                                 const float* __restrict__ F2, int shead,
                                                 const uint32_t* __restrict__ bitsT,
                                                 const bf16_t* __restrict__ VTt,
                                                 bf16_t* __restrict__ Hpart,
                                                 float* __restrict__ zpart,
                                                 int CT, int JR, int ZC, int TS) {
    const int wave = threadIdx.x >> 6, lane = threadIdx.x & 63;
    const int lr = lane & 15, kg = lane >> 4;
    const int c = blockIdx.x / JZG, jzg = blockIdx.x % JZG;
    const int rowb = blockIdx.y * 64;
    const int jz = jzg * 4 + wave;
    const int cb = c * 64;
    const float* gp  = g1 + (size_t)shead * c;
    const float* E2p = E2 + (size_t)shead * c;
    const float* F2p = F2 + (size_t)shead * c;
    const int steps = JR >> 5, jb0 = jz * JR;

    f32x4 acc[4][4], accz[4];
#pragma unroll
    for (int rt = 0; rt < 4; ++rt) {
        accz[rt] = 0.0f;
#pragma unroll
        for (int dt = 0; dt < 4; ++dt) acc[rt][dt] = 0.0f;
    }
    float gv[4];
#pragma unroll
    for (int rt = 0; rt < 4; ++rt) gv[rt] = gp[rowb + rt * 16 + lr];
    bf16x8 ones;
#pragma unroll
    for (int e = 0; e < 8; ++e) ones[e] = (bf16_t)(lr == 0 ? 1.0f : 0.0f);

    auto LOAD = [&](int jb, bf16x8* bfr, f32x4& e2a, f32x4& e2b, f32x4& f2a, f32x4& f2b,
                    uint32_t* bw) {
        const int jk = jb + kg * 8;
        const int jc = jb >> 5;
        e2a = *(const f32x4*)(E2p + jk);
        e2b = *(const f32x4*)(E2p + jk + 4);
        f2a = *(const f32x4*)(F2p + jk);
        f2b = *(const f32x4*)(F2p + jk + 4);
        const bf16_t* vb = VTt + (size_t)jc * TS + kg * 8;
#pragma unroll
        for (int dt = 0; dt < 4; ++dt)
            bfr[dt] = *(const bf16x8*)(vb + (size_t)(cb + dt * 16 + lr) * 32);
        const uint32_t* bb = bitsT + (size_t)jc * NN + rowb;
#pragma unroll
        for (int rt = 0; rt < 4; ++rt)
            bw[rt] = bb[rt * 16 + lr];
    };
    auto COMP = [&](const bf16x8* bfr, f32x4 e2a, f32x4 e2b, f32x4 f2a, f32x4 f2b,
                    const uint32_t* bw) {
#pragma unroll
        for (int rt = 0; rt < 4; ++rt) {
            uint32_t mb = (bw[rt] >> (kg * 8)) & 0xffu;
            bf16x8 af;
#pragma unroll
            for (int e = 0; e < 8; ++e) {
                float e2 = (e < 4) ? e2a[e] : e2b[e - 4];
                float f2 = (e < 4) ? f2a[e] : f2b[e - 4];
                float p = fmaxf(e2, gv[rt] * f2);
                p = (mb & (1u << e)) ? p : 0.0f;
                af[e] = (bf16_t)p;
            }
#pragma unroll
            for (int dt = 0; dt < 4; ++dt)
                acc[rt][dt] = __builtin_amdgcn_mfma_f32_16x16x32_bf16(af, bfr[dt], acc[rt][dt], 0, 0, 0);
            accz[rt] = __builtin_amdgcn_mfma_f32_16x16x32_bf16(af, ones, accz[rt], 0, 0, 0);
        }
    };

    bf16x8 bA[4], bB[4];
    f32x4 eaA, ebA, faA, fbA, eaB, ebB, faB, fbB;
    uint32_t wA[4], wB[4];
    LOAD(jb0, bA, eaA, ebA, faA, fbA, wA);
    for (int js = 0; js < steps - 2; js += 2) {
        LOAD(jb0 + (js + 1) * 32, bB, eaB, ebB, faB, fbB, wB);
        COMP(bA, eaA, ebA, faA, fbA, wA);
        LOAD(jb0 + (js + 2) * 32, bA, eaA, ebA, faA, fbA, wA);
        COMP(bB, eaB, ebB, faB, fbB, wB);
    }
    LOAD(jb0 + (steps - 1) * 32, bB, eaB, ebB, faB, fbB, wB);
    COMP(bA, eaA, ebA, faA, fbA, wA);
    COMP(bB, eaB, ebB, faB, fbB, wB);

    bf16_t* Hp = Hpart + (size_t)jz * NN * CT;
#pragma unroll
    for (int rt = 0; rt < 4; ++rt) {
#pragma unroll
        for (int dt = 0; dt < 4; ++dt)
#pragma unroll
            for (int r = 0; r < 4; ++r)
                Hp[(size_t)(rowb + rt * 16 + kg * 4 + r) * CT + cb + dt * 16 + lr] = (bf16_t)acc[rt][dt][r];
    }
    if (lr == 0 && (ZC > 1 || c == 0)) {
        int zi = jz * ZC + (ZC > 1 ? c : 0);
#pragma unroll
        for (int rt = 0; rt < 4; ++rt)
#pragma unroll
            for (int r = 0; r < 4; ++r)
                zpart[(size_t)zi * NN + rowb + rt * 16 + kg * 4 + r] = accz[rt][r];
    }
}

// ---- finalize layer 1: hcatb = bf16(ELU(sum H / sum Z)), 8 cols/thread
__global__ __launch_bounds__(256) void fin1_k(const bf16_t* __restrict__ Hpart,
                                              const float* __restrict__ zpart,
                                              bf16_t* __restrict__ hcatb) {
    int idx = blockIdx.x * 256 + threadIdx.x;   // < N*64
    int i = idx >> 6, col0 = (idx & 63) << 3, h = col0 >> 6;
    float Z = 0.f;
#pragma unroll
    for (int jz = 0; jz < 8; ++jz) Z += zpart[(size_t)(jz * 8 + h) * NN + i];
    float hs[8];
#pragma unroll
    for (int e = 0; e < 8; ++e) hs[e] = 0.f;
#pragma unroll
    for (int jz = 0; jz < 8; ++jz) {
        bf16x8 v = *(const bf16x8*)(Hpart + ((size_t)jz * NN + i) * 512 + col0);
#pragma unroll
        for (int e = 0; e < 8; ++e) hs[e] += (float)v[e];
    }
    float invZ = 1.0f / Z;
    bf16x8 o;
#pragma unroll
    for (int e = 0; e < 8; ++e) {
        float v = hs[e] * invZ;
        o[e] = (bf16_t)(v > 0.f ? v : expm1f(v));
    }
    *(bf16x8*)(hcatb + (size_t)i * 512 + col0) = o;
}

// ---- combine split-K gemm2 slices: VT2 (j-tiled) + g/E2/F2. block=128thr=1 row.
__global__ __launch_bounds__(128) void comb2_k(const float* __restrict__ Cp,
                                               const float* __restrict__ a1o,
                                               const float* __restrict__ a2o,
                                               bf16_t* __restrict__ VT2t,
                                               float* __restrict__ g1o,
                                               float* __restrict__ E2o,
                                               float* __restrict__ F2o) {
    int r = blockIdx.x, t = threadIdx.x;
    float w = 0.f;
#pragma unroll
    for (int z = 0; z < 4; ++z) w += Cp[((size_t)z * NN + r) * 128 + t];
    VT2t[(size_t)(r >> 5) * (128 * 32) + t * 32 + (r & 31)] = (bf16_t)w;
    float d1 = w * a1o[t], d2 = w * a2o[t];
#pragma unroll
    for (int o = 1; o < 64; o <<= 1) { d1 += __shfl_xor(d1, o); d2 += __shfl_xor(d2, o); }
    __shared__ float red[4];
    if ((t & 63) == 0) { red[(t >> 6) * 2 + 0] = d1; red[(t >> 6) * 2 + 1] = d2; }
    __syncthreads();
    if (t == 0) {
        float s1 = red[0] + red[2], s2 = red[1] + red[3];
        g1o[r] = exp2f(-0.8f * LOG2E * s1);
        E2o[r] = exp2f(LOG2E * s2);
        F2o[r] = exp2f(0.2f * LOG2E * s2);
    }
}

// ---- finalize layer 2: out fp32 = sum H / sum Z, 8 cols/thread
__global__ __launch_bounds__(256) void fin2_k(const bf16_t* __restrict__ Hpart,
                                              const float* __restrict__ zpart,
                                              float* __restrict__ out) {
    int idx = blockIdx.x * 256 + threadIdx.x;   // < N*16
    int i = idx >> 4, col0 = (idx & 15) << 3;
    float Z = 0.f;
#pragma unroll
    for (int jz = 0; jz < 16; ++jz) Z += zpart[(size_t)jz * NN + i];
    float hs[8];
#pragma unroll
    for (int e = 0; e < 8; ++e) hs[e] = 0.f;
#pragma unroll
    for (int jz = 0; jz < 16; ++jz) {
        bf16x8 v = *(const bf16x8*)(Hpart + ((size_t)jz * NN + i) * 128 + col0);
#pragma unroll
        for (int e = 0; e < 8; ++e) hs[e] += (float)v[e];
    }
    float invZ = 1.0f / Z;
    f32x4 o0, o1;
#pragma unroll
    for (int e = 0; e < 4; ++e) { o0[e] = hs[e] * invZ; o1[e] = hs[e + 4] * invZ; }
    *(f32x4*)(out + (size_t)i * 128 + col0) = o0;
    *(f32x4*)(out + (size_t)i * 128 + col0 + 4) = o1;
}

extern "C" void kernel_launch(void* const* d_in, const int* in_sizes, int n_in,
                              void* d_out, int out_size, void* d_ws, size_t ws_size,
                              hipStream_t stream) {
    const int N = 4096;
    const float* x       = (const float*)d_in[0];
    const int*   adj     = (const int*)d_in[1];
    const float* W_heads = (const float*)d_in[2];
    const float* a1h     = (const float*)d_in[3];
    const float* a2h     = (const float*)d_in[4];
    const float* W_out   = (const float*)d_in[5];
    const float* a1o     = (const float*)d_in[6];
    const float* a2o     = (const float*)d_in[7];
    (void)in_sizes; (void)n_in; (void)out_size; (void)ws_size;

    size_t off = 0;
    auto alloc = [&](size_t bytes) { size_t o = off; off = (off + bytes + 255) & ~(size_t)255; return o; };
    char* ws = (char*)d_ws;
    uint32_t* bitsT = (uint32_t*)(ws + alloc((size_t)N * N / 8));        // 2 MB
    bf16_t* VT1t    = (bf16_t*)(ws + alloc((size_t)512 * N * 2));        // 4 MB (tiled)
    bf16_t* hcatb   = (bf16_t*)(ws + alloc((size_t)N * 512 * 2));        // 4 MB
    bf16_t* WoutT   = (bf16_t*)(ws + alloc((size_t)128 * 512 * 2));      // 128 KB
    float*  g1h     = (float*)(ws + alloc((size_t)8 * N * 4));
    float*  E2h     = (float*)(ws + alloc((size_t)8 * N * 4));
    float*  F2h     = (float*)(ws + alloc((size_t)8 * N * 4));
    float*  g1o     = (float*)(ws + alloc((size_t)N * 4));
    float*  E2o     = (float*)(ws + alloc((size_t)N * 4));
    float*  F2o     = (float*)(ws + alloc((size_t)N * 4));
    bf16_t* VT2t    = (bf16_t*)(ws + alloc((size_t)128 * N * 2));        // 1 MB (tiled)
    float*  zpart   = (float*)(ws + alloc((size_t)64 * N * 4));          // 1 MB
    bf16_t* Hpart   = (bf16_t*)(ws + alloc((size_t)32 * 1024 * 1024));   // 32 MB
    // aliases into the Hpart region (temporally disjoint):
    bf16_t* xb    = (bf16_t*)Hpart;                       // dead after gemm1
    bf16_t* WT1   = (bf16_t*)((char*)Hpart + (4 << 20));  // dead after gemm1
    float*  Cpart = (float*)Hpart;                        // gemm2..comb2 only

    // 1. adjacency bitmask (transposed)
    hipLaunchKernelGGL(pack_bits_k, dim3(2048), dim3(256), 0, stream, adj, bitsT, N * N);
    // 2. prep conversions/transposes
    hipLaunchKernelGGL(prep_k, dim3(1024), dim3(256), 0, stream, x, W_heads, W_out, xb, WT1, WoutT);
    // 3. gemm1: VT1 tiled + g/E2/F2 per head  (4-wave blocks)
    hipLaunchKernelGGL((gemm_k<1, 0>), dim3(64, 8, 1), dim3(256), 0, stream,
                       xb, WT1, VT1t, (float*)nullptr, a1h, a2h, g1h, E2h, F2h, 512, 512, 512, 512);
    // 4. layer-1 aggregate: grid x=(head,jzgrp)=16, y=rowtile=64; jz = jzgrp*4+wave
    hipLaunchKernelGGL((gat_agg_k<2>), dim3(16, 64, 1), dim3(256), 0, stream,
                       g1h, E2h, F2h, N, bitsT, VT1t, Hpart, zpart, 512, 512, 8, 512 * 32);
    // 5. finalize 1 -> hcatb
    hipLaunchKernelGGL(fin1_k, dim3(1024), dim3(256), 0, stream, Hpart, zpart, hcatb);
    // 6. gemm2 split-K=4 -> Cpart  (4-wave blocks)
    hipLaunchKernelGGL((gemm_k<0, 1>), dim3(64, 2, 4), dim3(256), 0, stream,
                       hcatb, WoutT, (bf16_t*)nullptr, Cpart,
                       (const float*)nullptr, (const float*)nullptr,
                       (float*)nullptr, (float*)nullptr, (float*)nullptr, 512, 128, 128, 128);
    // 7. combine -> VT2 tiled, g1o/E2o/F2o
    hipLaunchKernelGGL(comb2_k, dim3(4096), dim3(128), 0, stream, Cpart, a1o, a2o, VT2t, g1o, E2o, F2o);
    // 8. layer-2 aggregate: grid x=(c,jzgrp)=8, y=rowtile=64; jz = jzgrp*4+wave
    hipLaunchKernelGGL((gat_agg_k<4>), dim3(8, 64, 1), dim3(256), 0, stream,
                       g1o, E2o, F2o, 0, bitsT, VT2t, Hpart, zpart, 128, 256, 1, 128 * 32);
    // 9. finalize 2 -> out
    hipLaunchKernelGGL(fin2_k, dim3(256), dim3(256), 0, stream, Hpart, zpart, (float*)d_out);
}